// Round 5
// baseline (1502.707 us; speedup 1.0000x reference)
//
#include <hip/hip_runtime.h>

#define N_NODES 100000
#define NNZ_E   3200000
#define SLOPE   0.25f
#define NBLK_SCAN 98   // ceil(100000/1024)
#define NBUK    6250   // ceil(100000/16), bucket = row >> 4

typedef __attribute__((ext_vector_type(8))) short bf16x8;
typedef __attribute__((ext_vector_type(4))) float f32x4;

// f32 -> bf16 round-to-nearest-even (bit trick)
__device__ __forceinline__ unsigned short f2b(float f) {
    union { float f; unsigned int u; } c; c.f = f;
    unsigned int u = c.u + 0x7fffu + ((c.u >> 16) & 1u);
    return (unsigned short)(u >> 16);
}
__device__ __forceinline__ float b2f_lo(unsigned int u) {
    union { unsigned int u; float f; } c; c.u = u << 16; return c.f;
}
__device__ __forceinline__ float b2f_hi(unsigned int u) {
    union { unsigned int u; float f; } c; c.u = u & 0xffff0000u; return c.f;
}

// async global->LDS, 16B per lane; LDS dest is wave-uniform base + lane*16
__device__ __forceinline__ void load_lds16(const unsigned short* gp, unsigned short* lp) {
    __builtin_amdgcn_global_load_lds(
        (const __attribute__((address_space(1))) void*)gp,
        (__attribute__((address_space(3))) void*)lp, 16, 0, 0);
}

// ---------------- CSR build ----------------
__global__ __launch_bounds__(256) void hist_kernel(const int* __restrict__ rows,
                                                   int* __restrict__ counts) {
    int e = blockIdx.x * blockDim.x + threadIdx.x;
    if (e < NNZ_E) atomicAdd(&counts[rows[e]], 1);
}

__global__ __launch_bounds__(256) void chunk_sum_kernel(const int* __restrict__ counts,
                                                        int* __restrict__ bsum) {
    int b = blockIdx.x, t = threadIdx.x;
    int base = b * 1024 + t * 4;
    int s = 0;
    if (base < N_NODES) {
        int4 v = *(const int4*)&counts[base];
        s = v.x + v.y + v.z + v.w;
    }
    __shared__ int red[256];
    red[t] = s; __syncthreads();
    for (int off = 128; off > 0; off >>= 1) {
        if (t < off) red[t] += red[t + off];
        __syncthreads();
    }
    if (t == 0) bsum[b] = red[0];
}

__global__ __launch_bounds__(128) void bsum_scan_kernel(const int* __restrict__ bsum,
                                                        int* __restrict__ boff) {
    int t = threadIdx.x;
    __shared__ int lds[128];
    int v = (t < NBLK_SCAN) ? bsum[t] : 0;
    lds[t] = v; __syncthreads();
    for (int off = 1; off < 128; off <<= 1) {
        int u = (t >= off) ? lds[t - off] : 0;
        __syncthreads();
        lds[t] += u;
        __syncthreads();
    }
    if (t < NBLK_SCAN) boff[t] = lds[t] - v;
}

__global__ __launch_bounds__(256) void scan_apply_kernel(const int* __restrict__ counts,
                                                         const int* __restrict__ boff,
                                                         int* __restrict__ row_off,
                                                         int* __restrict__ cursor) {
    int b = blockIdx.x, t = threadIdx.x;
    int base = b * 1024 + t * 4;
    int4 v = make_int4(0, 0, 0, 0);
    if (base < N_NODES) v = *(const int4*)&counts[base];
    int s = v.x + v.y + v.z + v.w;
    __shared__ int lds[256];
    lds[t] = s; __syncthreads();
    for (int off = 1; off < 256; off <<= 1) {
        int u = (t >= off) ? lds[t - off] : 0;
        __syncthreads();
        lds[t] += u;
        __syncthreads();
    }
    int run = boff[b] + lds[t] - s;
    if (base < N_NODES) {
        row_off[base + 0] = run; cursor[base + 0] = run; run += v.x;
        row_off[base + 1] = run; cursor[base + 1] = run; run += v.y;
        row_off[base + 2] = run; cursor[base + 2] = run; run += v.z;
        row_off[base + 3] = run; cursor[base + 3] = run; run += v.w;
    }
    if (b == 0 && t == 0) row_off[N_NODES] = NNZ_E;
}

// bucket cursors start at the bucket's CSR base (bucket regions == final regions)
__global__ __launch_bounds__(256) void bcur_init_kernel(const int* __restrict__ row_off,
                                                        int* __restrict__ bcur) {
    int b = blockIdx.x * blockDim.x + threadIdx.x;
    if (b < NBUK) bcur[b] = row_off[b * 16];  // 16*6249 = 99984 < N
}

// pass 1: scatter edges into 16-row buckets (dense, line-friendly writes)
__global__ __launch_bounds__(256) void bucket_scatter_kernel(const int* __restrict__ rows,
                                                             const int* __restrict__ cols,
                                                             const float* __restrict__ vals,
                                                             int* __restrict__ bcur,
                                                             int2* __restrict__ tmprc,
                                                             float* __restrict__ tmpv) {
    int e = blockIdx.x * blockDim.x + threadIdx.x;
    if (e < NNZ_E) {
        int r = rows[e];
        int pos = atomicAdd(&bcur[r >> 4], 1);
        tmprc[pos] = make_int2(r, cols[e]);
        tmpv[pos]  = vals[e];
    }
}

// pass 2: within-bucket scatter to exact CSR slot (writes stay in ~4KB window)
__global__ __launch_bounds__(256) void final_scatter_kernel(const int2* __restrict__ tmprc,
                                                            const float* __restrict__ tmpv,
                                                            int* __restrict__ cursor,
                                                            int2* __restrict__ epack) {
    int i = blockIdx.x * blockDim.x + threadIdx.x;
    if (i < NNZ_E) {
        int2 rc = tmprc[i];
        int pos = atomicAdd(&cursor[rc.x], 1);
        epack[pos] = make_int2(rc.y, __float_as_int(tmpv[i]));
    }
}

// ---------------- dtype prep ----------------
__global__ __launch_bounds__(256) void conv_kernel(const float* __restrict__ in,
                                                   unsigned short* __restrict__ out,
                                                   int n4) {
    int i = blockIdx.x * blockDim.x + threadIdx.x;
    if (i < n4) {
        float4 v = *(const float4*)&in[i << 2];
        ushort4 o;
        o.x = f2b(v.x); o.y = f2b(v.y); o.z = f2b(v.z); o.w = f2b(v.w);
        *(ushort4*)&out[i << 2] = o;
    }
}

__global__ __launch_bounds__(256) void wprep_kernel(const float* __restrict__ W,
                                                    unsigned short* __restrict__ Wt,
                                                    int K, int Nc) {
    int idx = blockIdx.x * blockDim.x + threadIdx.x;
    if (idx < K * Nc) {
        int n = idx / K, k = idx - n * K;
        Wt[idx] = f2b(W[(size_t)k * Nc + n]);
    }
}

// ---------------- bf16 MFMA GEMM (m97 structure) ----------------
__global__ __launch_bounds__(256) void gemm_bf16_128(
    const unsigned short* __restrict__ A,   // [M,K] bf16
    const unsigned short* __restrict__ Bt,  // [Nc,K] bf16
    unsigned short* __restrict__ C,         // [M,Nc] bf16
    int M, int K, int Nc)
{
    __shared__ __align__(16) unsigned short As[128 * 32];
    __shared__ __align__(16) unsigned short Bs[128 * 32];
    const int t = threadIdx.x;
    const int wave = t >> 6, lane = t & 63;
    const int wm = wave & 1, wn = wave >> 1;
    const int quad = lane >> 4, l16 = lane & 15;
    const int row0 = blockIdx.y * 128, col0 = blockIdx.x * 128;

    f32x4 acc[4][4];
#pragma unroll
    for (int mt = 0; mt < 4; ++mt)
#pragma unroll
        for (int nt = 0; nt < 4; ++nt) acc[mt][nt] = (f32x4){0.f, 0.f, 0.f, 0.f};

    const int sr0 = wave * 16 + (lane >> 2);
    const int sr1 = sr0 + 64;
    const int sc  = (lane & 3) << 3;

    int ra0 = row0 + sr0; if (ra0 > M - 1) ra0 = M - 1;
    int ra1 = row0 + sr1; if (ra1 > M - 1) ra1 = M - 1;
    const int rb0 = col0 + sr0;
    const int rb1 = col0 + sr1;

    for (int k0 = 0; k0 < K; k0 += 32) {
        __syncthreads();
        load_lds16(&A [(size_t)ra0 * K + k0 + sc], &As[(size_t)wave * 512]);
        load_lds16(&A [(size_t)ra1 * K + k0 + sc], &As[(size_t)(wave + 4) * 512]);
        load_lds16(&Bt[(size_t)rb0 * K + k0 + sc], &Bs[(size_t)wave * 512]);
        load_lds16(&Bt[(size_t)rb1 * K + k0 + sc], &Bs[(size_t)(wave + 4) * 512]);
        __syncthreads();

        bf16x8 af[4], bf[4];
#pragma unroll
        for (int mt = 0; mt < 4; ++mt)
            af[mt] = *(const bf16x8*)&As[(wm * 64 + mt * 16 + l16) * 32 + quad * 8];
#pragma unroll
        for (int nt = 0; nt < 4; ++nt)
            bf[nt] = *(const bf16x8*)&Bs[(wn * 64 + nt * 16 + l16) * 32 + quad * 8];
#pragma unroll
        for (int mt = 0; mt < 4; ++mt)
#pragma unroll
            for (int nt = 0; nt < 4; ++nt)
                acc[mt][nt] = __builtin_amdgcn_mfma_f32_16x16x32_bf16(
                    af[mt], bf[nt], acc[mt][nt], 0, 0, 0);
    }

#pragma unroll
    for (int mt = 0; mt < 4; ++mt)
#pragma unroll
        for (int r = 0; r < 4; ++r) {
            int row = row0 + wm * 64 + mt * 16 + quad * 4 + r;
            if (row < M) {
#pragma unroll
                for (int nt = 0; nt < 4; ++nt) {
                    int col = col0 + wn * 64 + nt * 16 + l16;
                    C[(size_t)row * Nc + col] = f2b(acc[mt][nt][r]);
                }
            }
        }
}

// ---------------- CSR SpMM, bf16 support gather, one wave per row ----------------
__global__ __launch_bounds__(256) void spmm256b_kernel(const int* __restrict__ row_off,
                                                       const int2* __restrict__ ep,
                                                       const unsigned short* __restrict__ sup,
                                                       const float* __restrict__ bias,
                                                       unsigned short* __restrict__ out) {
    int row = (blockIdx.x << 2) + (threadIdx.x >> 6);
    if (row >= N_NODES) return;
    int lane = threadIdx.x & 63;
    int s = row_off[row], e = row_off[row + 1];
    int cb = lane << 2;
    float a0 = 0.f, a1 = 0.f, a2 = 0.f, a3 = 0.f;
    int i = s;
    for (; i + 4 <= e; i += 4) {
        int2 p0 = ep[i], p1 = ep[i + 1], p2 = ep[i + 2], p3 = ep[i + 3];
        float v0 = __int_as_float(p0.y), v1 = __int_as_float(p1.y);
        float v2 = __int_as_float(p2.y), v3 = __int_as_float(p3.y);
        uint2 g0 = *(const uint2*)&sup[((size_t)p0.x << 8) + cb];
        uint2 g1 = *(const uint2*)&sup[((size_t)p1.x << 8) + cb];
        uint2 g2 = *(const uint2*)&sup[((size_t)p2.x << 8) + cb];
        uint2 g3 = *(const uint2*)&sup[((size_t)p3.x << 8) + cb];
        a0 += v0 * b2f_lo(g0.x); a1 += v0 * b2f_hi(g0.x);
        a2 += v0 * b2f_lo(g0.y); a3 += v0 * b2f_hi(g0.y);
        a0 += v1 * b2f_lo(g1.x); a1 += v1 * b2f_hi(g1.x);
        a2 += v1 * b2f_lo(g1.y); a3 += v1 * b2f_hi(g1.y);
        a0 += v2 * b2f_lo(g2.x); a1 += v2 * b2f_hi(g2.x);
        a2 += v2 * b2f_lo(g2.y); a3 += v2 * b2f_hi(g2.y);
        a0 += v3 * b2f_lo(g3.x); a1 += v3 * b2f_hi(g3.x);
        a2 += v3 * b2f_lo(g3.y); a3 += v3 * b2f_hi(g3.y);
    }
    for (; i < e; ++i) {
        int2 p0 = ep[i];
        float v0 = __int_as_float(p0.y);
        uint2 g0 = *(const uint2*)&sup[((size_t)p0.x << 8) + cb];
        a0 += v0 * b2f_lo(g0.x); a1 += v0 * b2f_hi(g0.x);
        a2 += v0 * b2f_lo(g0.y); a3 += v0 * b2f_hi(g0.y);
    }
    float4 bv = *(const float4*)&bias[cb];
    a0 += bv.x; a1 += bv.y; a2 += bv.z; a3 += bv.w;
    a0 = (a0 >= 0.f) ? a0 : SLOPE * a0;
    a1 = (a1 >= 0.f) ? a1 : SLOPE * a1;
    a2 = (a2 >= 0.f) ? a2 : SLOPE * a2;
    a3 = (a3 >= 0.f) ? a3 : SLOPE * a3;
    ushort4 o; o.x = f2b(a0); o.y = f2b(a1); o.z = f2b(a2); o.w = f2b(a3);
    *(ushort4*)&out[((size_t)row << 8) + cb] = o;
}

__global__ __launch_bounds__(256) void spmm128f_kernel(const int* __restrict__ row_off,
                                                       const int2* __restrict__ ep,
                                                       const unsigned short* __restrict__ sup,
                                                       const float* __restrict__ bias,
                                                       float* __restrict__ out) {
    int row = (blockIdx.x << 2) + (threadIdx.x >> 6);
    if (row >= N_NODES) return;
    int lane = threadIdx.x & 63;
    int s = row_off[row], e = row_off[row + 1];
    int cb = lane << 1;
    float a0 = 0.f, a1 = 0.f;
    int i = s;
    for (; i + 4 <= e; i += 4) {
        int2 p0 = ep[i], p1 = ep[i + 1], p2 = ep[i + 2], p3 = ep[i + 3];
        float v0 = __int_as_float(p0.y), v1 = __int_as_float(p1.y);
        float v2 = __int_as_float(p2.y), v3 = __int_as_float(p3.y);
        unsigned int g0 = *(const unsigned int*)&sup[((size_t)p0.x << 7) + cb];
        unsigned int g1 = *(const unsigned int*)&sup[((size_t)p1.x << 7) + cb];
        unsigned int g2 = *(const unsigned int*)&sup[((size_t)p2.x << 7) + cb];
        unsigned int g3 = *(const unsigned int*)&sup[((size_t)p3.x << 7) + cb];
        a0 += v0 * b2f_lo(g0); a1 += v0 * b2f_hi(g0);
        a0 += v1 * b2f_lo(g1); a1 += v1 * b2f_hi(g1);
        a0 += v2 * b2f_lo(g2); a1 += v2 * b2f_hi(g2);
        a0 += v3 * b2f_lo(g3); a1 += v3 * b2f_hi(g3);
    }
    for (; i < e; ++i) {
        int2 p0 = ep[i];
        float v0 = __int_as_float(p0.y);
        unsigned int g0 = *(const unsigned int*)&sup[((size_t)p0.x << 7) + cb];
        a0 += v0 * b2f_lo(g0); a1 += v0 * b2f_hi(g0);
    }
    float2 bv = *(const float2*)&bias[cb];
    a0 += bv.x; a1 += bv.y;
    a0 = (a0 >= 0.f) ? a0 : SLOPE * a0;
    a1 = (a1 >= 0.f) ? a1 : SLOPE * a1;
    *(float2*)&out[((size_t)row << 7) + cb] = make_float2(a0, a1);
}

// ---------------- launch ----------------
extern "C" void kernel_launch(void* const* d_in, const int* in_sizes, int n_in,
                              void* d_out, int out_size, void* d_ws, size_t ws_size,
                              hipStream_t stream) {
    const float* x     = (const float*)d_in[0];
    const int*   arows = (const int*)d_in[1];
    const int*   acols = (const int*)d_in[2];
    const float* avals = (const float*)d_in[3];
    const float* W1 = (const float*)d_in[4];
    const float* b1 = (const float*)d_in[5];
    const float* W2 = (const float*)d_in[6];
    const float* b2 = (const float*)d_in[7];
    const float* W3 = (const float*)d_in[8];
    const float* b3 = (const float*)d_in[9];
    float* out = (float*)d_out;

    char* ws = (char*)d_ws;
    unsigned short* xb   = (unsigned short*)(ws);                 // 100000*512 bf16
    unsigned short* bufS = (unsigned short*)(ws + 102400000);     // 100000*256 bf16
    unsigned short* bufH = (unsigned short*)(ws + 153600000);     // 100000*256 bf16
    int2*  epack = (int2*)(ws + 204800000);                       // NNZ int2
    int*   roff = (int*)  (ws + 230400000);                       // N+1 i32
    int*   curs = (int*)  (ws + 230800128);                       // N i32 (dead after final_scatter)
    int*   cnts = (int*)  (ws + 231200128);                       // N i32 (dead after scan_apply)
    // overlays:
    unsigned short* Wt1 = (unsigned short*)(ws + 231200128);      // over cnts
    unsigned short* Wt2 = (unsigned short*)(ws + 230800128);      // over curs
    unsigned short* Wt3 = (unsigned short*)(ws + 230800128 + 131072);
    // bucket-scatter temporaries overlay xb (conv runs after final_scatter)
    int2*  tmprc = (int2*)(ws);                                   // NNZ int2 = 25.6 MB
    float* tmpv  = (float*)(ws + 25600000);                       // NNZ f32 = 12.8 MB
    // scan/bucket scratch overlays bufH (first written by spmm L1)
    int* bsum = (int*)(ws + 153600000);
    int* boff = (int*)(ws + 153600000 + 512);
    int* bcur = (int*)(ws + 153600000 + 1024);                    // NBUK i32 = 25 KB

    // CSR build
    hipMemsetAsync(cnts, 0, N_NODES * sizeof(int), stream);
    hist_kernel<<<NNZ_E / 256, 256, 0, stream>>>(arows, cnts);
    chunk_sum_kernel<<<NBLK_SCAN, 256, 0, stream>>>(cnts, bsum);
    bsum_scan_kernel<<<1, 128, 0, stream>>>(bsum, boff);
    scan_apply_kernel<<<NBLK_SCAN, 256, 0, stream>>>(cnts, boff, roff, curs);
    wprep_kernel<<<(512 * 256 + 255) / 256, 256, 0, stream>>>(W1, Wt1, 512, 256); // cnts dead
    bcur_init_kernel<<<(NBUK + 255) / 256, 256, 0, stream>>>(roff, bcur);
    bucket_scatter_kernel<<<NNZ_E / 256, 256, 0, stream>>>(arows, acols, avals, bcur, tmprc, tmpv);
    final_scatter_kernel<<<NNZ_E / 256, 256, 0, stream>>>(tmprc, tmpv, curs, epack);
    wprep_kernel<<<(256 * 256 + 255) / 256, 256, 0, stream>>>(W2, Wt2, 256, 256); // curs dead
    wprep_kernel<<<(256 * 128 + 255) / 256, 256, 0, stream>>>(W3, Wt3, 256, 128);

    // x -> bf16 (after scatter passes: xb overlays tmprc/tmpv)
    conv_kernel<<<(100000 * 512 / 4 + 255) / 256, 256, 0, stream>>>(x, xb, 100000 * 512 / 4);

    const int gyc = (N_NODES + 127) / 128;  // 782

    // layer 1
    gemm_bf16_128<<<dim3(2, gyc), 256, 0, stream>>>(xb, Wt1, bufS, N_NODES, 512, 256);
    spmm256b_kernel<<<25000, 256, 0, stream>>>(roff, epack, bufS, b1, bufH);
    // layer 2
    gemm_bf16_128<<<dim3(2, gyc), 256, 0, stream>>>(bufH, Wt2, bufS, N_NODES, 256, 256);
    spmm256b_kernel<<<25000, 256, 0, stream>>>(roff, epack, bufS, b2, bufH);
    // layer 3
    gemm_bf16_128<<<dim3(1, gyc), 256, 0, stream>>>(bufH, Wt3, bufS, N_NODES, 256, 128);
    spmm128f_kernel<<<25000, 256, 0, stream>>>(roff, epack, bufS, b3, out);
}